// Round 7
// baseline (540.304 us; speedup 1.0000x reference)
//
#include <hip/hip_runtime.h>
#include <hip/hip_bf16.h>
#include <stdint.h>

#define D 1024
#define TEMP_INV (1.0f / 0.92f)
#define LOG2E 1.44269504f
#define EPS 1e-6f

typedef float f32x4_t __attribute__((ext_vector_type(4)));
typedef int   i32x4_t __attribute__((ext_vector_type(4)));
typedef int   i32x8_t __attribute__((ext_vector_type(8)));

typedef __attribute__((address_space(3))) void as3_void;
typedef const __attribute__((address_space(1))) void as1_void_c;

__device__ __forceinline__ void async_copy16(const uint8_t* g, uint8_t* l) {
    __builtin_amdgcn_global_load_lds((as1_void_c*)g, (as3_void*)l, 16, 0, 0);
}

// ---------------------------------------------------------------------------
// Kernel 1: convert Q,Neg to fp8 e4m3; compute iq = T^-1*log2e/qn,
// in = 1/nn, s1 = exp(pos_sim/T) (exact fp32 path); zero rowsum + done ctr.
// One WAVE per row (4 rows/block).  [identical to round 5 + done-counter init]
// ---------------------------------------------------------------------------
__global__ __launch_bounds__(256) void prep_kernel(
    const float* __restrict__ q, const float* __restrict__ p,
    const float* __restrict__ neg,
    uint8_t* __restrict__ Qb, uint8_t* __restrict__ Nb,
    float* __restrict__ iq, float* __restrict__ inx,
    float* __restrict__ s1, float* __restrict__ rowsum,
    int* __restrict__ done, int B)
{
    const int lane = threadIdx.x & 63;
    const int wid  = threadIdx.x >> 6;
    const int row  = blockIdx.x * 4 + wid;

    if (blockIdx.x == 0 && threadIdx.x == 0) *done = 0;

    if (row < B) {
        const float4* qr = (const float4*)(q + (size_t)row * D);
        const float4* pr = (const float4*)(p + (size_t)row * D);
        int* qo = (int*)(Qb + (size_t)row * D);
        float qq = 0.f, pp = 0.f, qp = 0.f;
        #pragma unroll
        for (int i = 0; i < 4; ++i) {
            const int idx = i * 64 + lane;
            const float4 qv = qr[idx];
            const float4 pv = pr[idx];
            int pk = __builtin_amdgcn_cvt_pk_fp8_f32(qv.x, qv.y, 0, false);
            pk     = __builtin_amdgcn_cvt_pk_fp8_f32(qv.z, qv.w, pk, true);
            qo[idx] = pk;
            qq += qv.x*qv.x + qv.y*qv.y + qv.z*qv.z + qv.w*qv.w;
            pp += pv.x*pv.x + pv.y*pv.y + pv.z*pv.z + pv.w*pv.w;
            qp += qv.x*pv.x + qv.y*pv.y + qv.z*pv.z + qv.w*pv.w;
        }
        #pragma unroll
        for (int off = 32; off > 0; off >>= 1) {
            qq += __shfl_down(qq, off, 64);
            pp += __shfl_down(pp, off, 64);
            qp += __shfl_down(qp, off, 64);
        }
        if (lane == 0) {
            float qnv = sqrtf(qq);
            iq[row] = (TEMP_INV * LOG2E) / fmaxf(qnv, 1e-20f);
            float den = fmaxf(qnv * sqrtf(pp), EPS);
            s1[row] = expf((qp / den) * TEMP_INV);   // exact reference path
            rowsum[row] = 0.0f;
        }
    } else {
        const int r2 = row - B;
        const float4* nr = (const float4*)(neg + (size_t)r2 * D);
        int* no = (int*)(Nb + (size_t)r2 * D);
        float ss = 0.f;
        #pragma unroll
        for (int i = 0; i < 4; ++i) {
            const int idx = i * 64 + lane;
            const float4 nv = nr[idx];
            int pk = __builtin_amdgcn_cvt_pk_fp8_f32(nv.x, nv.y, 0, false);
            pk     = __builtin_amdgcn_cvt_pk_fp8_f32(nv.z, nv.w, pk, true);
            no[idx] = pk;
            ss += nv.x*nv.x + nv.y*nv.y + nv.z*nv.z + nv.w*nv.w;
        }
        #pragma unroll
        for (int off = 32; off > 0; off >>= 1) ss += __shfl_down(ss, off, 64);
        if (lane == 0) inx[r2] = 1.0f / fmaxf(sqrtf(ss), 1e-20f);
    }
}

// ---------------------------------------------------------------------------
// Kernel 2: fused C = Qb * Nb^T via MX-fp8 mfma_scale 16x16x128 (unit scales),
// epilogue exp2(dot*iq_i*in_j) + row-sum; K-loop/swizzle bit-identical to
// round 5 (measured 0 bank conflicts). NEW: last-finishing block performs the
// loss reduction (done-counter + fences; agent-scope atomic loads of rowsum
// for cross-XCD visibility).
// ---------------------------------------------------------------------------
__global__ __launch_bounds__(256) void gemm_exp_rowsum(
    const uint8_t* __restrict__ Qb, const uint8_t* __restrict__ Nb,
    const float* __restrict__ iq, const float* __restrict__ inx,
    float* __restrict__ rowsum, const float* __restrict__ s1,
    int* __restrict__ done, float* __restrict__ out, int B, int N)
{
    __shared__ uint8_t As[128 * 128];   // 16 KB
    __shared__ uint8_t Bs[128 * 128];   // 16 KB
    __shared__ float red[4];
    __shared__ int is_last;

    const int tid = threadIdx.x;
    const int i0 = blockIdx.y * 128;   // Q rows
    const int j0 = blockIdx.x * 128;   // Neg rows

    const int lane = tid & 63;
    const int wid  = tid >> 6;
    const int wm   = wid & 1;
    const int wn   = wid >> 1;
    const int quad = lane >> 4;
    const int lc   = lane & 15;
    const int xsw  = lc & 7;

    f32x4_t acc[4][4];
    #pragma unroll
    for (int mi = 0; mi < 4; ++mi)
        #pragma unroll
        for (int ni = 0; ni < 4; ++ni)
            acc[mi][ni] = (f32x4_t){0.f, 0.f, 0.f, 0.f};

    // staging (round-5 verified, 0 conflicts): thread t: row r_in=t>>3,
    // slot s=t&7, fetches chunk pi^-1(s^(r_in&7)), pi(c)=(c>>1)|((c&1)<<2);
    // LDS dest = base + t*16.
    const int r_in = tid >> 3;
    const int slot = tid & 7;
    const int v    = slot ^ (r_in & 7);
    const int csw  = ((v & 3) << 1) | (v >> 2);
    const uint8_t* ga = Qb + (size_t)(i0 + r_in) * D + csw * 16;
    const uint8_t* gb = Nb + (size_t)(j0 + r_in) * D + csw * 16;
    uint8_t* la = As + tid * 16;
    uint8_t* lb = Bs + tid * 16;

    const uint8_t* Abase = As + (size_t)(wm * 64 + lc) * 128;
    const uint8_t* Bbase = Bs + (size_t)(wn * 64 + lc) * 128;
    const int slo = (quad ^ xsw) * 16;
    const int shi = slo ^ 64;

    union Frag { i32x8_t v8; i32x4_t v4[2]; };

    for (int kt = 0; kt < D; kt += 128) {
        __syncthreads();
        #pragma unroll
        for (int c = 0; c < 4; ++c) {
            async_copy16(ga + kt + c * (32 * D), la + c * 4096);
            async_copy16(gb + kt + c * (32 * D), lb + c * 4096);
        }
        __syncthreads();

        Frag bfr[4];
        #pragma unroll
        for (int ni = 0; ni < 4; ++ni) {
            bfr[ni].v4[0] = *(const i32x4_t*)(Bbase + ni * 2048 + slo);
            bfr[ni].v4[1] = *(const i32x4_t*)(Bbase + ni * 2048 + shi);
        }
        #pragma unroll
        for (int mi = 0; mi < 4; ++mi) {
            Frag af;
            af.v4[0] = *(const i32x4_t*)(Abase + mi * 2048 + slo);
            af.v4[1] = *(const i32x4_t*)(Abase + mi * 2048 + shi);
            #pragma unroll
            for (int ni = 0; ni < 4; ++ni)
                acc[mi][ni] = __builtin_amdgcn_mfma_scale_f32_16x16x128_f8f6f4(
                    af.v8, bfr[ni].v8, acc[mi][ni],
                    0 /*A=fp8 e4m3*/, 0 /*B=fp8 e4m3*/,
                    0, 127, 0, 127 /*unit scales*/);
        }
    }

    // Epilogue: exp2(dot * iq_i * in_j); row-reduce; atomicAdd.
    float inl[4];
    #pragma unroll
    for (int ni = 0; ni < 4; ++ni)
        inl[ni] = inx[j0 + wn * 64 + ni * 16 + lc];

    #pragma unroll
    for (int mi = 0; mi < 4; ++mi) {
        const int rbase = i0 + wm * 64 + mi * 16 + quad * 4;
        const float4 qv = *(const float4*)&iq[rbase];
        float qa[4] = {qv.x, qv.y, qv.z, qv.w};
        float rs[4] = {0.f, 0.f, 0.f, 0.f};
        #pragma unroll
        for (int ni = 0; ni < 4; ++ni) {
            #pragma unroll
            for (int r = 0; r < 4; ++r)
                rs[r] += __builtin_amdgcn_exp2f(acc[mi][ni][r] * qa[r] * inl[ni]);
        }
        #pragma unroll
        for (int m = 1; m < 16; m <<= 1) {
            #pragma unroll
            for (int r = 0; r < 4; ++r) rs[r] += __shfl_xor(rs[r], m, 64);
        }
        if (lc == 0) {
            #pragma unroll
            for (int r = 0; r < 4; ++r) atomicAdd(&rowsum[rbase + r], rs[r]);
        }
    }

    // ---- last-block finalize ----
    __threadfence();   // order our rowsum atomics before the counter bump
    if (tid == 0) {
        int old = __hip_atomic_fetch_add(done, 1, __ATOMIC_ACQ_REL,
                                         __HIP_MEMORY_SCOPE_AGENT);
        is_last = (old == (int)(gridDim.x * gridDim.y) - 1);
    }
    __syncthreads();
    if (!is_last) return;

    __threadfence();   // acquire: others' rowsum writes now visible
    const float invN = 1.0f / (float)N;
    float accl = 0.f;
    for (int b = tid; b < B; b += 256) {
        float a  = s1[b];
        float s2 = __hip_atomic_load(&rowsum[b], __ATOMIC_RELAXED,
                                     __HIP_MEMORY_SCOPE_AGENT) * invN;
        accl += __logf(a + s2) - __logf(a);
    }
    #pragma unroll
    for (int off = 32; off > 0; off >>= 1) accl += __shfl_down(accl, off, 64);
    if ((tid & 63) == 0) red[tid >> 6] = accl;
    __syncthreads();
    if (tid == 0)
        out[0] = (red[0] + red[1] + red[2] + red[3]) / (float)B;
}

extern "C" void kernel_launch(void* const* d_in, const int* in_sizes, int n_in,
                              void* d_out, int out_size, void* d_ws, size_t ws_size,
                              hipStream_t stream) {
    const float* q   = (const float*)d_in[0];
    const float* p   = (const float*)d_in[1];
    const float* neg = (const float*)d_in[2];
    const int B = in_sizes[0] / D;
    const int N = in_sizes[2] / D;

    char* ws = (char*)d_ws;
    uint8_t* Qb     = (uint8_t*)ws;
    uint8_t* Nb     = (uint8_t*)(ws + (size_t)B * D);
    float*   iq     = (float*)(ws + (size_t)(B + N) * D);
    float*   inx    = iq + B;
    float*   s1     = inx + N;
    float*   rowsum = s1 + B;
    int*     done   = (int*)(rowsum + B);

    prep_kernel<<<(B + N) / 4, 256, 0, stream>>>(q, p, neg, Qb, Nb, iq, inx,
                                                 s1, rowsum, done, B);
    gemm_exp_rowsum<<<dim3(N / 128, B / 128), 256, 0, stream>>>(
        Qb, Nb, iq, inx, rowsum, s1, done, (float*)d_out, B, N);
}

// Round 8
// 242.155 us; speedup vs baseline: 2.2312x; 2.2312x over previous
//
#include <hip/hip_runtime.h>
#include <hip/hip_bf16.h>
#include <stdint.h>

#define D 1024
#define TEMP_INV (1.0f / 0.92f)
#define LOG2E 1.44269504f
#define EPS 1e-6f

typedef float f32x4_t __attribute__((ext_vector_type(4)));
typedef int   i32x4_t __attribute__((ext_vector_type(4)));
typedef int   i32x8_t __attribute__((ext_vector_type(8)));

typedef __attribute__((address_space(3))) void as3_void;
typedef const __attribute__((address_space(1))) void as1_void_c;

__device__ __forceinline__ void async_copy16(const uint8_t* g, uint8_t* l) {
    __builtin_amdgcn_global_load_lds((as1_void_c*)g, (as3_void*)l, 16, 0, 0);
}

// ---------------------------------------------------------------------------
// Kernel 1: convert Q,Neg to fp8 e4m3; iq = T^-1*log2e/qn, inx = 1/nn,
// s1 = exp(pos_sim/T) (exact fp32 path); zero rowsum. One WAVE per row.
// [bit-identical to round 5]
// ---------------------------------------------------------------------------
__global__ __launch_bounds__(256) void prep_kernel(
    const float* __restrict__ q, const float* __restrict__ p,
    const float* __restrict__ neg,
    uint8_t* __restrict__ Qb, uint8_t* __restrict__ Nb,
    float* __restrict__ iq, float* __restrict__ inx,
    float* __restrict__ s1, float* __restrict__ rowsum, int B)
{
    const int lane = threadIdx.x & 63;
    const int wid  = threadIdx.x >> 6;
    const int row  = blockIdx.x * 4 + wid;

    if (row < B) {
        const float4* qr = (const float4*)(q + (size_t)row * D);
        const float4* pr = (const float4*)(p + (size_t)row * D);
        int* qo = (int*)(Qb + (size_t)row * D);
        float qq = 0.f, pp = 0.f, qp = 0.f;
        #pragma unroll
        for (int i = 0; i < 4; ++i) {
            const int idx = i * 64 + lane;
            const float4 qv = qr[idx];
            const float4 pv = pr[idx];
            int pk = __builtin_amdgcn_cvt_pk_fp8_f32(qv.x, qv.y, 0, false);
            pk     = __builtin_amdgcn_cvt_pk_fp8_f32(qv.z, qv.w, pk, true);
            qo[idx] = pk;
            qq += qv.x*qv.x + qv.y*qv.y + qv.z*qv.z + qv.w*qv.w;
            pp += pv.x*pv.x + pv.y*pv.y + pv.z*pv.z + pv.w*pv.w;
            qp += qv.x*pv.x + qv.y*pv.y + qv.z*pv.z + qv.w*pv.w;
        }
        #pragma unroll
        for (int off = 32; off > 0; off >>= 1) {
            qq += __shfl_down(qq, off, 64);
            pp += __shfl_down(pp, off, 64);
            qp += __shfl_down(qp, off, 64);
        }
        if (lane == 0) {
            float qnv = sqrtf(qq);
            iq[row] = (TEMP_INV * LOG2E) / fmaxf(qnv, 1e-20f);
            float den = fmaxf(qnv * sqrtf(pp), EPS);
            s1[row] = expf((qp / den) * TEMP_INV);   // exact reference path
            rowsum[row] = 0.0f;
        }
    } else {
        const int r2 = row - B;
        const float4* nr = (const float4*)(neg + (size_t)r2 * D);
        int* no = (int*)(Nb + (size_t)r2 * D);
        float ss = 0.f;
        #pragma unroll
        for (int i = 0; i < 4; ++i) {
            const int idx = i * 64 + lane;
            const float4 nv = nr[idx];
            int pk = __builtin_amdgcn_cvt_pk_fp8_f32(nv.x, nv.y, 0, false);
            pk     = __builtin_amdgcn_cvt_pk_fp8_f32(nv.z, nv.w, pk, true);
            no[idx] = pk;
            ss += nv.x*nv.x + nv.y*nv.y + nv.z*nv.z + nv.w*nv.w;
        }
        #pragma unroll
        for (int off = 32; off > 0; off >>= 1) ss += __shfl_down(ss, off, 64);
        if (lane == 0) inx[r2] = 1.0f / fmaxf(sqrtf(ss), 1e-20f);
    }
}

// ---------------------------------------------------------------------------
// Kernel 2: fused C = Qb * Nb^T via MX-fp8 mfma_scale 16x16x128 (unit scales),
// epilogue exp2(dot*iq_i*in_j) + row-sum + atomicAdd.
// NEW this round: 128x256 tile (BM=128 Q-rows, BN=256 Neg-rows), BK=128.
// Doubles MFMA per barrier-pair (16->32 per wave per kt) for 1.5x staged
// bytes; LDS 48 KB. Swizzle is per-128B-row -> identical 0-conflict pattern
// (rounds 4-5 measured 0). Waves 2x2: wm in {0,1} x 64 i-rows, wn in {0,1} x
// 128 j-cols; acc[4][8].
// ---------------------------------------------------------------------------
__global__ __launch_bounds__(256) void gemm_exp_rowsum(
    const uint8_t* __restrict__ Qb, const uint8_t* __restrict__ Nb,
    const float* __restrict__ iq, const float* __restrict__ inx,
    float* __restrict__ rowsum)
{
    __shared__ uint8_t As[128 * 128];   // 16 KB
    __shared__ uint8_t Bs[256 * 128];   // 32 KB

    const int tid = threadIdx.x;
    const int i0 = blockIdx.y * 128;   // Q rows
    const int j0 = blockIdx.x * 256;   // Neg rows

    const int lane = tid & 63;
    const int wid  = tid >> 6;
    const int wm   = wid & 1;          // i half
    const int wn   = wid >> 1;         // j half
    const int quad = lane >> 4;
    const int lc   = lane & 15;
    const int xsw  = lc & 7;

    f32x4_t acc[4][8];
    #pragma unroll
    for (int mi = 0; mi < 4; ++mi)
        #pragma unroll
        for (int ni = 0; ni < 8; ++ni)
            acc[mi][ni] = (f32x4_t){0.f, 0.f, 0.f, 0.f};

    // staging (verified 0-conflict): thread t: row r_in = t>>3 (per 32-row
    // round), slot s = t&7, fetches chunk pi^-1(s^(r_in&7)),
    // pi(c) = (c>>1)|((c&1)<<2); LDS dest = base + t*16.
    const int r_in = tid >> 3;
    const int slot = tid & 7;
    const int v    = slot ^ (r_in & 7);
    const int csw  = ((v & 3) << 1) | (v >> 2);
    const uint8_t* ga = Qb + (size_t)(i0 + r_in) * D + csw * 16;
    const uint8_t* gb = Nb + (size_t)(j0 + r_in) * D + csw * 16;
    uint8_t* la = As + tid * 16;
    uint8_t* lb = Bs + tid * 16;

    const uint8_t* Abase = As + (size_t)(wm * 64 + lc) * 128;
    const uint8_t* Bbase = Bs + (size_t)(wn * 128 + lc) * 128;
    const int slo = (quad ^ xsw) * 16;
    const int shi = slo ^ 64;

    union Frag { i32x8_t v8; i32x4_t v4[2]; };

    for (int kt = 0; kt < D; kt += 128) {
        __syncthreads();
        #pragma unroll
        for (int c = 0; c < 4; ++c)
            async_copy16(ga + kt + c * (32 * D), la + c * 4096);
        #pragma unroll
        for (int c = 0; c < 8; ++c)
            async_copy16(gb + kt + c * (32 * D), lb + c * 4096);
        __syncthreads();

        Frag af[4];
        #pragma unroll
        for (int mi = 0; mi < 4; ++mi) {
            af[mi].v4[0] = *(const i32x4_t*)(Abase + mi * 2048 + slo);
            af[mi].v4[1] = *(const i32x4_t*)(Abase + mi * 2048 + shi);
        }
        #pragma unroll
        for (int ni = 0; ni < 8; ++ni) {
            Frag bf;
            bf.v4[0] = *(const i32x4_t*)(Bbase + ni * 2048 + slo);
            bf.v4[1] = *(const i32x4_t*)(Bbase + ni * 2048 + shi);
            #pragma unroll
            for (int mi = 0; mi < 4; ++mi)
                acc[mi][ni] = __builtin_amdgcn_mfma_scale_f32_16x16x128_f8f6f4(
                    af[mi].v8, bf.v8, acc[mi][ni],
                    0 /*A=fp8 e4m3*/, 0 /*B=fp8 e4m3*/,
                    0, 127, 0, 127 /*unit scales*/);
        }
    }

    // Epilogue: exp2(dot * iq_i * in_j); row-reduce; atomicAdd.
    // C/D layout (16x16): col = lane&15, row = quad*4 + reg.
    float inl[8];
    #pragma unroll
    for (int ni = 0; ni < 8; ++ni)
        inl[ni] = inx[j0 + wn * 128 + ni * 16 + lc];

    #pragma unroll
    for (int mi = 0; mi < 4; ++mi) {
        const int rbase = i0 + wm * 64 + mi * 16 + quad * 4;
        const float4 qv = *(const float4*)&iq[rbase];
        float qa[4] = {qv.x, qv.y, qv.z, qv.w};
        float rs[4] = {0.f, 0.f, 0.f, 0.f};
        #pragma unroll
        for (int ni = 0; ni < 8; ++ni) {
            #pragma unroll
            for (int r = 0; r < 4; ++r)
                rs[r] += __builtin_amdgcn_exp2f(acc[mi][ni][r] * qa[r] * inl[ni]);
        }
        #pragma unroll
        for (int m = 1; m < 16; m <<= 1) {
            #pragma unroll
            for (int r = 0; r < 4; ++r) rs[r] += __shfl_xor(rs[r], m, 64);
        }
        if (lc == 0) {
            #pragma unroll
            for (int r = 0; r < 4; ++r) atomicAdd(&rowsum[rbase + r], rs[r]);
        }
    }
}

// ---------------------------------------------------------------------------
// Kernel 3: loss = mean_b( log(s1+s2) - log(s1) ), s2 = rowsum/N.
// ---------------------------------------------------------------------------
__global__ __launch_bounds__(256) void finalize_kernel(
    const float* __restrict__ s1, const float* __restrict__ rowsum,
    float* __restrict__ out, int B, float invN)
{
    __shared__ float red[4];
    const float4* s4 = (const float4*)s1;
    const float4* r4 = (const float4*)rowsum;
    float acc = 0.f;
    for (int i = threadIdx.x; i < B / 4; i += 256) {
        float4 a = s4[i];
        float4 s = r4[i];
        acc += __logf(a.x + s.x * invN) - __logf(a.x);
        acc += __logf(a.y + s.y * invN) - __logf(a.y);
        acc += __logf(a.z + s.z * invN) - __logf(a.z);
        acc += __logf(a.w + s.w * invN) - __logf(a.w);
    }
    #pragma unroll
    for (int off = 32; off > 0; off >>= 1) acc += __shfl_down(acc, off, 64);
    if ((threadIdx.x & 63) == 0) red[threadIdx.x >> 6] = acc;
    __syncthreads();
    if (threadIdx.x == 0)
        out[0] = (red[0] + red[1] + red[2] + red[3]) / (float)B;
}

extern "C" void kernel_launch(void* const* d_in, const int* in_sizes, int n_in,
                              void* d_out, int out_size, void* d_ws, size_t ws_size,
                              hipStream_t stream) {
    const float* q   = (const float*)d_in[0];
    const float* p   = (const float*)d_in[1];
    const float* neg = (const float*)d_in[2];
    const int B = in_sizes[0] / D;
    const int N = in_sizes[2] / D;

    char* ws = (char*)d_ws;
    uint8_t* Qb     = (uint8_t*)ws;
    uint8_t* Nb     = (uint8_t*)(ws + (size_t)B * D);
    float*   iq     = (float*)(ws + (size_t)(B + N) * D);
    float*   inx    = iq + B;
    float*   s1     = inx + N;
    float*   rowsum = s1 + B;

    prep_kernel<<<(B + N) / 4, 256, 0, stream>>>(q, p, neg, Qb, Nb, iq, inx, s1, rowsum, B);
    gemm_exp_rowsum<<<dim3(N / 256, B / 128), 256, 0, stream>>>(Qb, Nb, iq, inx, rowsum);
    finalize_kernel<<<1, 256, 0, stream>>>(s1, rowsum, (float*)d_out, B, 1.0f / (float)N);
}